// Round 5
// baseline (923.767 us; speedup 1.0000x reference)
//
#include <hip/hip_runtime.h>
#include <math.h>

#define N_NODES 50000
#define N_EDGES 800000
#define SCAN_B 512
#define SCAN_NBLK ((N_NODES + SCAN_B - 1) / SCAN_B)   // 98

typedef unsigned short u16;
typedef unsigned int u32;
typedef _Float16 f16;
typedef __fp16 h2 __attribute__((ext_vector_type(2)));   // matches cvt_pkrtz / fdot2

union U32H2 { u32 u; h2 h; };
__device__ __forceinline__ h2 u2h(u32 x) { U32H2 t; t.u = x; return t.h; }
__device__ __forceinline__ u32 h2u(h2 x) { U32H2 t; t.h = x; return t.u; }

// ---------------- K0: edge MLP (f16 out) + fused degree count ----------------
__global__ void k_edge_mlp(const float* __restrict__ edge_attr,
                           const float* __restrict__ Wm1, const float* __restrict__ bm1,
                           const float* __restrict__ Wm2, const float* __restrict__ bm2,
                           const int* __restrict__ dst, int* __restrict__ deg,
                           f16* __restrict__ e16) {
    int e = blockIdx.x * blockDim.x + threadIdx.x;
    if (e >= N_EDGES) return;
    atomicAdd(&deg[dst[e]], 1);
    const float4* ap = (const float4*)(edge_attr + (size_t)e * 16);
    float a[16];
    #pragma unroll
    for (int i = 0; i < 4; i++) {
        float4 r = ap[i];
        a[4*i] = r.x; a[4*i+1] = r.y; a[4*i+2] = r.z; a[4*i+3] = r.w;
    }
    float g1[16];
    #pragma unroll
    for (int j = 0; j < 16; j++) {
        float v = bm1[j];
        #pragma unroll
        for (int k = 0; k < 16; k++) v = fmaf(a[k], Wm1[k*16 + j], v);
        g1[j] = 0.5f * v * (1.0f + erff(v * 0.70710678118654752f));
    }
    float o[16];
    #pragma unroll
    for (int j = 0; j < 16; j++) {
        float v = bm2[j];
        #pragma unroll
        for (int k = 0; k < 16; k++) v = fmaf(g1[k], Wm2[k*16 + j], v);
        o[j] = v;
    }
    u32 w[8];
    #pragma unroll
    for (int k2 = 0; k2 < 8; k2++) w[k2] = h2u(__builtin_amdgcn_cvt_pkrtz(o[2*k2], o[2*k2+1]));
    uint4* op = (uint4*)(e16 + (size_t)e * 16);
    op[0] = make_uint4(w[0], w[1], w[2], w[3]);
    op[1] = make_uint4(w[4], w[5], w[6], w[7]);
}

// ---------------- K1: node features ----------------
// block = 512 (8 waves): wave w<4 -> XL side gate w (LDS-transposed out),
// w>=4 -> XR side gate w-4 (direct [n][inst][c] out).
template<int K>
__global__ void __launch_bounds__(512)
k_node_feats(const float* __restrict__ in,
             const float* __restrict__ Wl, const float* __restrict__ bl,
             const float* __restrict__ Wr, const float* __restrict__ br,
             f16* __restrict__ XLt,   // [n][64][4] f16
             f16* __restrict__ XR,    // [n][8][64] f16
             int inst_base) {
    __shared__ alignas(8) f16 sx[64 * 4];
    int w = threadIdx.x >> 6;
    int c = threadIdx.x & 63;
    int g = w & 3;
    bool isR = w >= 4;
    const float* W = isR ? Wr : Wl;
    const float* bias = isR ? br : bl;
    float wcol[K];
    #pragma unroll
    for (int k = 0; k < K; k++) wcol[k] = W[(g*K + k)*64 + c];
    float b = bias[g*64 + c];
    for (int n = blockIdx.x; n < N_NODES; n += gridDim.x) {
        const float* row = in + (size_t)n * K;   // wave-uniform
        float acc = b;
        #pragma unroll
        for (int k = 0; k < K; k++) acc = fmaf(row[k], wcol[k], acc);
        if (isR) {
            XR[((size_t)n*8 + inst_base + g)*64 + c] = (f16)acc;
        } else {
            sx[c*4 + g] = (f16)acc;
        }
        __syncthreads();
        if (w == 0) {
            uint2 v = *(const uint2*)&sx[c*4];
            *(uint2*)(XLt + ((size_t)n*64 + c)*4) = v;
        }
        __syncthreads();
    }
}

// ---------------- K2: CSR build (scan + fill) ----------------
__global__ void __launch_bounds__(SCAN_B)
k_scan1(const int* __restrict__ deg, int* __restrict__ tmp, int* __restrict__ partials) {
    __shared__ int s[SCAN_B];
    int t = threadIdx.x;
    int i = blockIdx.x * SCAN_B + t;
    int v = (i < N_NODES) ? deg[i] : 0;
    s[t] = v;
    __syncthreads();
    #pragma unroll
    for (int off = 1; off < SCAN_B; off <<= 1) {
        int add = (t >= off) ? s[t - off] : 0;
        __syncthreads();
        s[t] += add;
        __syncthreads();
    }
    if (i < N_NODES) tmp[i] = s[t];
    if (t == SCAN_B - 1) partials[blockIdx.x] = s[SCAN_B - 1];
}

__global__ void __launch_bounds__(64)
k_scan2(int* __restrict__ partials) {
    int lane = threadIdx.x;
    int carry = 0;
    for (int base = 0; base < SCAN_NBLK; base += 64) {
        int i = base + lane;
        int v = (i < SCAN_NBLK) ? partials[i] : 0;
        #pragma unroll
        for (int off = 1; off < 64; off <<= 1) {
            int u = __shfl_up(v, off);
            if (lane >= off) v += u;
        }
        if (i < SCAN_NBLK) partials[i] = v + carry;
        carry += __shfl(v, 63);
    }
}

__global__ void __launch_bounds__(SCAN_B)
k_scan3(const int* __restrict__ tmp, const int* __restrict__ partials,
        int* __restrict__ row_ptr, int* __restrict__ cursor) {
    int i = blockIdx.x * SCAN_B + threadIdx.x;
    if (i < N_NODES) {
        int b = blockIdx.x;
        int off = (b > 0) ? partials[b - 1] : 0;
        row_ptr[i + 1] = off + tmp[i];
        cursor[i] = 0;
        if (i == 0) row_ptr[0] = 0;
    }
}

__global__ void k_fill(const int* __restrict__ dst, const int* __restrict__ row_ptr,
                       int* __restrict__ cursor, int* __restrict__ sorted_eid) {
    int e = blockIdx.x * blockDim.x + threadIdx.x;
    if (e < N_EDGES) {
        int d = dst[e];
        int pos = atomicAdd(&cursor[d], 1);
        sorted_eid[row_ptr[d] + pos] = e;
    }
}

// ---------------- K3: fused GATv2 x8 + LSTM + LayerNorm ----------------
// 256-thread blocks = 4 waves; each wave owns one node; lane = output channel
__global__ void __launch_bounds__(256)
k_gat_main(const int* __restrict__ src_idx,
           const f16* __restrict__ e16,
           const f16* __restrict__ XLx, const f16* __restrict__ XLh,
           const f16* __restrict__ XR,
           const int* __restrict__ row_ptr, const int* __restrict__ sorted_eid,
           const float* __restrict__ Wex, const float* __restrict__ Weh,
           const float* __restrict__ attx, const float* __restrict__ atth,
           const float* __restrict__ biasx, const float* __restrict__ biash,
           const float* __restrict__ c_prev,
           const float* __restrict__ ln_g, const float* __restrict__ ln_b,
           float* __restrict__ out) {
    int wv = threadIdx.x >> 6;
    int lane = threadIdx.x & 63;
    int n = blockIdx.x * 4 + wv;          // 50000 = 12500*4
    int c = lane;
    int hh = c >> 5;
    int ch = c & 31;

    float attv[8];
    #pragma unroll
    for (int g = 0; g < 4; g++) {
        attv[g]     = attx[(g*2 + hh)*32 + ch];
        attv[4 + g] = atth[(g*2 + hh)*32 + ch];
    }
    // We columns for this lane, packed f16 pairs along k, fed to v_dot2_f32_f16
    h2 wef[8][8];
    #pragma unroll
    for (int g = 0; g < 4; g++) {
        #pragma unroll
        for (int k2 = 0; k2 < 8; k2++) {
            wef[g][k2]     = __builtin_amdgcn_cvt_pkrtz(Wex[(g*16 + 2*k2)*64 + c],
                                                        Wex[(g*16 + 2*k2 + 1)*64 + c]);
            wef[4 + g][k2] = __builtin_amdgcn_cvt_pkrtz(Weh[(g*16 + 2*k2)*64 + c],
                                                        Weh[(g*16 + 2*k2 + 1)*64 + c]);
        }
    }
    float xr8[8], acc[8], den[8];
    #pragma unroll
    for (int i = 0; i < 8; i++) {
        xr8[i] = (float)XR[((size_t)n*8 + i)*64 + c];
        acc[i] = 0.f;
        den[i] = 0.f;
    }
    int start = row_ptr[n];
    int end = row_ptr[n + 1];
    for (int base = start; base < end; base += 64) {
        int rem = end - base;
        int cnt = rem < 64 ? rem : 64;
        int eid_v = 0, src_v = 0;
        if (base + lane < end) {
            eid_v = sorted_eid[base + lane];
            src_v = src_idx[eid_v];
        }
        for (int j = 0; j < cnt; j++) {
            int eid = __builtin_amdgcn_readlane(eid_v, j);
            int sn  = __builtin_amdgcn_readlane(src_v, j);
            const uint4* ep = (const uint4*)(e16 + (size_t)eid * 16);
            uint4 q0 = ep[0], q1 = ep[1];
            h2 es[8] = {u2h(q0.x), u2h(q0.y), u2h(q0.z), u2h(q0.w),
                        u2h(q1.x), u2h(q1.y), u2h(q1.z), u2h(q1.w)};
            uint2 lx = *(const uint2*)(XLx + ((size_t)sn*64 + c)*4);
            uint2 lh = *(const uint2*)(XLh + ((size_t)sn*64 + c)*4);
            h2 x01 = u2h(lx.x), x23 = u2h(lx.y);
            h2 hp01 = u2h(lh.x), hp23 = u2h(lh.y);
            float xls[8] = {(float)x01[0],  (float)x01[1],  (float)x23[0],  (float)x23[1],
                            (float)hp01[0], (float)hp01[1], (float)hp23[0], (float)hp23[1]};
            h2 tp[4];
            #pragma unroll
            for (int pr = 0; pr < 4; pr++) {
                float t2[2];
                #pragma unroll
                for (int s = 0; s < 2; s++) {
                    int inst = pr*2 + s;
                    float m = xls[inst] + xr8[inst];
                    #pragma unroll
                    for (int k2 = 0; k2 < 8; k2++)
                        m = __builtin_amdgcn_fdot2(es[k2], wef[inst][k2], m, false);
                    float mr = fmaxf(m, 0.f) + 0.2f * fminf(m, 0.f);  // leaky_relu
                    t2[s] = mr * attv[inst];
                }
                tp[pr] = __builtin_amdgcn_cvt_pkrtz(t2[0], t2[1]);
            }
            // packed-f16 butterfly reduce over the 32 lanes of each head
            #pragma unroll
            for (int off = 16; off >= 1; off >>= 1) {
                #pragma unroll
                for (int pr = 0; pr < 4; pr++)
                    tp[pr] = tp[pr] + u2h((u32)__shfl_xor((int)h2u(tp[pr]), off));
            }
            #pragma unroll
            for (int inst = 0; inst < 8; inst++) {
                float s = (float)tp[inst >> 1][inst & 1];
                // scores tiny (|s| << 1): exp without max-subtraction is equivalent
                float p = __expf(s);
                den[inst] += p;
                acc[inst] = fmaf(p, xls[inst], acc[inst]);
            }
        }
    }
    float gates[4];
    #pragma unroll
    for (int g = 0; g < 4; g++) {
        float ax = acc[g]     / (den[g]     + 1e-16f) + biasx[g*64 + c];
        float ah = acc[4 + g] / (den[4 + g] + 1e-16f) + biash[g*64 + c];
        gates[g] = ax + ah;
    }
    float it = 1.f / (1.f + __expf(-gates[0]));
    float ft = 1.f / (1.f + __expf(-gates[1]));
    float ot = 1.f / (1.f + __expf(-gates[2]));
    float gt = tanhf(gates[3]);
    float cp = c_prev[(size_t)n*64 + c];
    float ct = ft * cp + it * gt;
    float ht = ot * tanhf(ct);
    float s1 = ht;
    #pragma unroll
    for (int off = 32; off >= 1; off >>= 1) s1 += __shfl_xor(s1, off);
    float mu = s1 * (1.f / 64.f);
    float d = ht - mu;
    float s2 = d * d;
    #pragma unroll
    for (int off = 32; off >= 1; off >>= 1) s2 += __shfl_xor(s2, off);
    float var = s2 * (1.f / 64.f);
    float y = d * rsqrtf(var + 1e-5f) * ln_g[c] + ln_b[c];
    out[(size_t)n*64 + c] = y;
    out[(size_t)(N_NODES + n)*64 + c] = ct;
}

extern "C" void kernel_launch(void* const* d_in, const int* in_sizes, int n_in,
                              void* d_out, int out_size, void* d_ws, size_t ws_size,
                              hipStream_t stream) {
    const float* x_t    = (const float*)d_in[0];
    const float* h_prev = (const float*)d_in[1];
    const float* c_prev = (const float*)d_in[2];
    const int*   ei     = (const int*)d_in[3];
    const float* eattr  = (const float*)d_in[4];
    const float* Wm1    = (const float*)d_in[5];
    const float* bm1    = (const float*)d_in[6];
    const float* Wm2    = (const float*)d_in[7];
    const float* bm2    = (const float*)d_in[8];
    const float* Wlx    = (const float*)d_in[9];
    const float* blx    = (const float*)d_in[10];
    const float* Wrx    = (const float*)d_in[11];
    const float* brx    = (const float*)d_in[12];
    const float* Wex    = (const float*)d_in[13];
    const float* attx   = (const float*)d_in[14];
    const float* biasx  = (const float*)d_in[15];
    const float* Wlh    = (const float*)d_in[16];
    const float* blh    = (const float*)d_in[17];
    const float* Wrh    = (const float*)d_in[18];
    const float* brh    = (const float*)d_in[19];
    const float* Weh    = (const float*)d_in[20];
    const float* atth   = (const float*)d_in[21];
    const float* biash  = (const float*)d_in[22];
    const float* ln_g   = (const float*)d_in[23];
    const float* ln_b   = (const float*)d_in[24];

    char* ws = (char*)d_ws;
    f16*   e16     = (f16*)(ws + 0);              // 25,600,000 B
    f16*   XLx     = (f16*)(ws + 25600000);       // 25,600,000 B  [n][64][4]
    f16*   XLh     = (f16*)(ws + 51200000);       // 25,600,000 B  [n][64][4]
    f16*   XR      = (f16*)(ws + 76800000);       // 51,200,000 B  [n][8][64]
    int*   row_ptr = (int*)(ws + 128000000);      //    200,704 B
    int*   degcur  = (int*)(ws + 128200704);      //    200,704 B
    int*   sorted  = (int*)(ws + 128401408);      //  3,200,000 B
    int*   scan_tmp = (int*)(ws + 128401408);     // overlaps sorted (dead before k_fill)
    int*   partials = (int*)(ws + 128401408 + 204800);

    const int* srcp = ei;
    const int* dstp = ei + N_EDGES;

    (void)hipMemsetAsync(degcur, 0, N_NODES * sizeof(int), stream);

    k_edge_mlp<<<(N_EDGES + 255) / 256, 256, 0, stream>>>(eattr, Wm1, bm1, Wm2, bm2,
                                                          dstp, degcur, e16);
    k_node_feats<32><<<6250, 512, 0, stream>>>(x_t, Wlx, blx, Wrx, brx, XLx, XR, 0);
    k_node_feats<64><<<6250, 512, 0, stream>>>(h_prev, Wlh, blh, Wrh, brh, XLh, XR, 4);
    k_scan1<<<SCAN_NBLK, SCAN_B, 0, stream>>>(degcur, scan_tmp, partials);
    k_scan2<<<1, 64, 0, stream>>>(partials);
    k_scan3<<<SCAN_NBLK, SCAN_B, 0, stream>>>(scan_tmp, partials, row_ptr, degcur);
    k_fill<<<(N_EDGES + 255) / 256, 256, 0, stream>>>(dstp, row_ptr, degcur, sorted);
    k_gat_main<<<N_NODES / 4, 256, 0, stream>>>(srcp, e16, XLx, XLh, XR, row_ptr, sorted,
                                                Wex, Weh, attx, atth, biasx, biash,
                                                c_prev, ln_g, ln_b, (float*)d_out);
}

// Round 6
// 771.444 us; speedup vs baseline: 1.1975x; 1.1975x over previous
//
#include <hip/hip_runtime.h>
#include <math.h>

#define N_NODES 50000
#define N_EDGES 800000
#define SCAN_B 512
#define SCAN_NBLK ((N_NODES + SCAN_B - 1) / SCAN_B)   // 98

typedef unsigned short u16;
typedef unsigned int u32;
typedef _Float16 f16;
typedef __fp16 h2 __attribute__((ext_vector_type(2)));   // matches cvt_pkrtz / fdot2

union U32H2 { u32 u; h2 h; };
__device__ __forceinline__ h2 u2h(u32 x) { U32H2 t; t.u = x; return t.h; }
__device__ __forceinline__ u32 h2u(h2 x) { U32H2 t; t.h = x; return t.u; }

// DPP cross-lane move (VALU pipe). CTRL: 0xB1=xor1(quad), 0x4E=xor2(quad),
// 0x124=row_ror:4, 0x128=row_ror:8. Rotation-reduce: every lane of a 16-row
// ends with the row sum after steps 1,2,ror4,ror8.
template<int CTRL>
__device__ __forceinline__ h2 dppmov(h2 x) {
    return u2h((u32)__builtin_amdgcn_update_dpp(0, (int)h2u(x), CTRL, 0xF, 0xF, true));
}
__device__ __forceinline__ h2 swz16(h2 x) {   // lane ^= 16 within each 32-group
    return u2h((u32)__builtin_amdgcn_ds_swizzle((int)h2u(x), 0x401F));
}

// ---------------- K0: edge MLP (f16 out) + fused degree count ----------------
__global__ void k_edge_mlp(const float* __restrict__ edge_attr,
                           const float* __restrict__ Wm1, const float* __restrict__ bm1,
                           const float* __restrict__ Wm2, const float* __restrict__ bm2,
                           const int* __restrict__ dst, int* __restrict__ deg,
                           f16* __restrict__ e16) {
    int e = blockIdx.x * blockDim.x + threadIdx.x;
    if (e >= N_EDGES) return;
    atomicAdd(&deg[dst[e]], 1);
    const float4* ap = (const float4*)(edge_attr + (size_t)e * 16);
    float a[16];
    #pragma unroll
    for (int i = 0; i < 4; i++) {
        float4 r = ap[i];
        a[4*i] = r.x; a[4*i+1] = r.y; a[4*i+2] = r.z; a[4*i+3] = r.w;
    }
    float g1[16];
    #pragma unroll
    for (int j = 0; j < 16; j++) {
        float v = bm1[j];
        #pragma unroll
        for (int k = 0; k < 16; k++) v = fmaf(a[k], Wm1[k*16 + j], v);
        g1[j] = 0.5f * v * (1.0f + erff(v * 0.70710678118654752f));
    }
    float o[16];
    #pragma unroll
    for (int j = 0; j < 16; j++) {
        float v = bm2[j];
        #pragma unroll
        for (int k = 0; k < 16; k++) v = fmaf(g1[k], Wm2[k*16 + j], v);
        o[j] = v;
    }
    u32 w[8];
    #pragma unroll
    for (int k2 = 0; k2 < 8; k2++) w[k2] = h2u(__builtin_amdgcn_cvt_pkrtz(o[2*k2], o[2*k2+1]));
    uint4* op = (uint4*)(e16 + (size_t)e * 16);
    op[0] = make_uint4(w[0], w[1], w[2], w[3]);
    op[1] = make_uint4(w[4], w[5], w[6], w[7]);
}

// ---------------- K1: node features -> XLt/XRt [n][c][8 inst] f16 ------------
// 512 threads = 8 waves: wave w<4 -> XL side gate w; w>=4 -> XR side gate w-4.
template<int K>
__global__ void __launch_bounds__(512)
k_node_feats(const float* __restrict__ in,
             const float* __restrict__ Wl, const float* __restrict__ bl,
             const float* __restrict__ Wr, const float* __restrict__ br,
             f16* __restrict__ XLt, f16* __restrict__ XRt, int inst_base) {
    int w = threadIdx.x >> 6;
    int c = threadIdx.x & 63;
    int g = w & 3;
    bool isR = w >= 4;
    const float* W = isR ? Wr : Wl;
    const float* bias = isR ? br : bl;
    f16* out = isR ? XRt : XLt;
    int inst = inst_base + g;
    float wcol[K];
    #pragma unroll
    for (int k = 0; k < K; k++) wcol[k] = W[(g*K + k)*64 + c];
    float b = bias[g*64 + c];
    for (int n = blockIdx.x; n < N_NODES; n += gridDim.x) {
        const float* row = in + (size_t)n * K;   // wave-uniform -> scalar loads
        float acc = b;
        #pragma unroll
        for (int k = 0; k < K; k++) acc = fmaf(row[k], wcol[k], acc);
        out[((size_t)n*64 + c)*8 + inst] = (f16)acc;
    }
}

// ---------------- K2: CSR build (scan + fill) ----------------
__global__ void __launch_bounds__(SCAN_B)
k_scan1(const int* __restrict__ deg, int* __restrict__ tmp, int* __restrict__ partials) {
    __shared__ int s[SCAN_B];
    int t = threadIdx.x;
    int i = blockIdx.x * SCAN_B + t;
    int v = (i < N_NODES) ? deg[i] : 0;
    s[t] = v;
    __syncthreads();
    #pragma unroll
    for (int off = 1; off < SCAN_B; off <<= 1) {
        int add = (t >= off) ? s[t - off] : 0;
        __syncthreads();
        s[t] += add;
        __syncthreads();
    }
    if (i < N_NODES) tmp[i] = s[t];
    if (t == SCAN_B - 1) partials[blockIdx.x] = s[SCAN_B - 1];
}

__global__ void __launch_bounds__(64)
k_scan2(int* __restrict__ partials) {
    int lane = threadIdx.x;
    int carry = 0;
    for (int base = 0; base < SCAN_NBLK; base += 64) {
        int i = base + lane;
        int v = (i < SCAN_NBLK) ? partials[i] : 0;
        #pragma unroll
        for (int off = 1; off < 64; off <<= 1) {
            int u = __shfl_up(v, off);
            if (lane >= off) v += u;
        }
        if (i < SCAN_NBLK) partials[i] = v + carry;
        carry += __shfl(v, 63);
    }
}

__global__ void __launch_bounds__(SCAN_B)
k_scan3(const int* __restrict__ tmp, const int* __restrict__ partials,
        int* __restrict__ row_ptr, int* __restrict__ cursor) {
    int i = blockIdx.x * SCAN_B + threadIdx.x;
    if (i < N_NODES) {
        int b = blockIdx.x;
        int off = (b > 0) ? partials[b - 1] : 0;
        row_ptr[i + 1] = off + tmp[i];
        cursor[i] = 0;
        if (i == 0) row_ptr[0] = 0;
    }
}

// fill sorted with (eid, src) pairs so the main kernel has no dependent gather
__global__ void k_fill(const int* __restrict__ src, const int* __restrict__ dst,
                       const int* __restrict__ row_ptr,
                       int* __restrict__ cursor, int2* __restrict__ sorted_es) {
    int e = blockIdx.x * blockDim.x + threadIdx.x;
    if (e < N_EDGES) {
        int d = dst[e];
        int s = src[e];
        int pos = atomicAdd(&cursor[d], 1);
        sorted_es[row_ptr[d] + pos] = make_int2(e, s);
    }
}

// ---------------- K3: fused GATv2 x8 + LSTM + LayerNorm ----------------
// 256-thread blocks = 4 waves; each wave owns one node; lane = output channel.
// 2-deep software pipeline on the per-edge loads; DPP rotation-reduce.
__global__ void __launch_bounds__(256)
k_gat_main(const f16* __restrict__ e16,
           const f16* __restrict__ XLt, const f16* __restrict__ XRt,
           const int* __restrict__ row_ptr, const int2* __restrict__ sorted_es,
           const float* __restrict__ Wex, const float* __restrict__ Weh,
           const float* __restrict__ attx, const float* __restrict__ atth,
           const float* __restrict__ biasx, const float* __restrict__ biash,
           const float* __restrict__ c_prev,
           const float* __restrict__ ln_g, const float* __restrict__ ln_b,
           float* __restrict__ out) {
    int wv = threadIdx.x >> 6;
    int lane = threadIdx.x & 63;
    int n = blockIdx.x * 4 + wv;          // 50000 = 12500*4
    int c = lane;
    int hh = c >> 5;
    int ch = c & 31;

    // att, packed by inst pairs (pr covers inst 2pr, 2pr+1)
    h2 attp[4];
    #pragma unroll
    for (int pr = 0; pr < 4; pr++) {
        float a0, a1;
        int i0 = 2*pr, i1 = 2*pr + 1;
        a0 = (i0 < 4) ? attx[(i0*2 + hh)*32 + ch] : atth[((i0-4)*2 + hh)*32 + ch];
        a1 = (i1 < 4) ? attx[(i1*2 + hh)*32 + ch] : atth[((i1-4)*2 + hh)*32 + ch];
        attp[pr] = __builtin_amdgcn_cvt_pkrtz(a0, a1);
    }
    // We columns for this lane, packed f16 pairs along k, fed to v_dot2_f32_f16
    h2 wef[8][8];
    #pragma unroll
    for (int g = 0; g < 4; g++) {
        #pragma unroll
        for (int k2 = 0; k2 < 8; k2++) {
            wef[g][k2]     = __builtin_amdgcn_cvt_pkrtz(Wex[(g*16 + 2*k2)*64 + c],
                                                        Wex[(g*16 + 2*k2 + 1)*64 + c]);
            wef[4 + g][k2] = __builtin_amdgcn_cvt_pkrtz(Weh[(g*16 + 2*k2)*64 + c],
                                                        Weh[(g*16 + 2*k2 + 1)*64 + c]);
        }
    }
    // xr row for this node (one dwordx4), packed by inst pairs
    h2 xrp[4];
    {
        uint4 rx = *(const uint4*)(XRt + ((size_t)n*64 + c)*8);
        xrp[0] = u2h(rx.x); xrp[1] = u2h(rx.y); xrp[2] = u2h(rx.z); xrp[3] = u2h(rx.w);
    }
    h2 accp[4], denp[4];
    #pragma unroll
    for (int pr = 0; pr < 4; pr++) { accp[pr] = (h2)0; denp[pr] = (h2)0; }

    int start = row_ptr[n];
    int end = row_ptr[n + 1];
    for (int base = start; base < end; base += 64) {
        int rem = end - base;
        int cnt = rem < 64 ? rem : 64;
        int2 ev = make_int2(0, 0);
        if (base + lane < end) ev = sorted_es[base + lane];
        int eid_v = ev.x, src_v = ev.y;

        // 2-slot software pipeline: loads for edge j issued at j-2's compute
        uint4 qa0, qa1, xa, qb0, qb1, xb;
        auto issueA = [&](int j) {
            int eid = __builtin_amdgcn_readlane(eid_v, j);
            int sn  = __builtin_amdgcn_readlane(src_v, j);
            const uint4* ep = (const uint4*)(e16 + (size_t)eid * 16);
            qa0 = ep[0]; qa1 = ep[1];
            xa = *(const uint4*)(XLt + ((size_t)sn*64 + c)*8);
        };
        auto issueB = [&](int j) {
            int eid = __builtin_amdgcn_readlane(eid_v, j);
            int sn  = __builtin_amdgcn_readlane(src_v, j);
            const uint4* ep = (const uint4*)(e16 + (size_t)eid * 16);
            qb0 = ep[0]; qb1 = ep[1];
            xb = *(const uint4*)(XLt + ((size_t)sn*64 + c)*8);
        };
        auto compute = [&](uint4 q0, uint4 q1, uint4 xl) {
            h2 es[8] = {u2h(q0.x), u2h(q0.y), u2h(q0.z), u2h(q0.w),
                        u2h(q1.x), u2h(q1.y), u2h(q1.z), u2h(q1.w)};
            h2 xlp[4] = {u2h(xl.x), u2h(xl.y), u2h(xl.z), u2h(xl.w)};
            float m[8];
            #pragma unroll
            for (int pr = 0; pr < 4; pr++) {
                h2 s = xlp[pr] + xrp[pr];          // v_pk_add_f16
                m[2*pr]   = (float)s[0];
                m[2*pr+1] = (float)s[1];
            }
            #pragma unroll
            for (int inst = 0; inst < 8; inst++) {
                #pragma unroll
                for (int k2 = 0; k2 < 8; k2++)
                    m[inst] = __builtin_amdgcn_fdot2(es[k2], wef[inst][k2], m[inst], false);
            }
            h2 tp[4];
            #pragma unroll
            for (int pr = 0; pr < 4; pr++) {
                h2 mm = __builtin_amdgcn_cvt_pkrtz(m[2*pr], m[2*pr+1]);
                h2 mx = __builtin_elementwise_max(mm, (h2)0);
                h2 mn = __builtin_elementwise_min(mm, (h2)0);
                h2 mr = mn * (h2)0.2f16 + mx;      // leaky_relu, packed
                tp[pr] = mr * attp[pr];
            }
            // rotation-reduce within 16-row (DPP, VALU pipe), then xor16 (1 DS op)
            #pragma unroll
            for (int pr = 0; pr < 4; pr++) tp[pr] = tp[pr] + dppmov<0xB1>(tp[pr]);
            #pragma unroll
            for (int pr = 0; pr < 4; pr++) tp[pr] = tp[pr] + dppmov<0x4E>(tp[pr]);
            #pragma unroll
            for (int pr = 0; pr < 4; pr++) tp[pr] = tp[pr] + dppmov<0x124>(tp[pr]);
            #pragma unroll
            for (int pr = 0; pr < 4; pr++) tp[pr] = tp[pr] + dppmov<0x128>(tp[pr]);
            #pragma unroll
            for (int pr = 0; pr < 4; pr++) tp[pr] = tp[pr] + swz16(tp[pr]);
            // scores tiny: exp without max-subtraction is equivalent
            #pragma unroll
            for (int pr = 0; pr < 4; pr++) {
                float p0 = __expf((float)tp[pr][0]);
                float p1 = __expf((float)tp[pr][1]);
                h2 pp = __builtin_amdgcn_cvt_pkrtz(p0, p1);
                denp[pr] = denp[pr] + pp;
                accp[pr] = __builtin_elementwise_fma(pp, xlp[pr], accp[pr]);
            }
        };

        if (cnt > 0) issueA(0);
        if (cnt > 1) issueB(1);
        int j = 0;
        while (j < cnt) {
            uint4 q0 = qa0, q1 = qa1, xl = xa;
            if (j + 2 < cnt) issueA(j + 2);
            compute(q0, q1, xl);
            j++;
            if (j >= cnt) break;
            q0 = qb0; q1 = qb1; xl = xb;
            if (j + 2 < cnt) issueB(j + 2);
            compute(q0, q1, xl);
            j++;
        }
    }
    float gates[4];
    #pragma unroll
    for (int g = 0; g < 4; g++) {
        float ax = (float)accp[g >> 1][g & 1] / ((float)denp[g >> 1][g & 1] + 1e-16f)
                   + biasx[g*64 + c];
        int i = 4 + g;
        float ah = (float)accp[i >> 1][i & 1] / ((float)denp[i >> 1][i & 1] + 1e-16f)
                   + biash[g*64 + c];
        gates[g] = ax + ah;
    }
    float it = 1.f / (1.f + __expf(-gates[0]));
    float ft = 1.f / (1.f + __expf(-gates[1]));
    float ot = 1.f / (1.f + __expf(-gates[2]));
    float gt = tanhf(gates[3]);
    float cp = c_prev[(size_t)n*64 + c];
    float ct = ft * cp + it * gt;
    float ht = ot * tanhf(ct);
    float s1 = ht;
    #pragma unroll
    for (int off = 32; off >= 1; off >>= 1) s1 += __shfl_xor(s1, off);
    float mu = s1 * (1.f / 64.f);
    float d = ht - mu;
    float s2 = d * d;
    #pragma unroll
    for (int off = 32; off >= 1; off >>= 1) s2 += __shfl_xor(s2, off);
    float var = s2 * (1.f / 64.f);
    float y = d * rsqrtf(var + 1e-5f) * ln_g[c] + ln_b[c];
    out[(size_t)n*64 + c] = y;
    out[(size_t)(N_NODES + n)*64 + c] = ct;
}

extern "C" void kernel_launch(void* const* d_in, const int* in_sizes, int n_in,
                              void* d_out, int out_size, void* d_ws, size_t ws_size,
                              hipStream_t stream) {
    const float* x_t    = (const float*)d_in[0];
    const float* h_prev = (const float*)d_in[1];
    const float* c_prev = (const float*)d_in[2];
    const int*   ei     = (const int*)d_in[3];
    const float* eattr  = (const float*)d_in[4];
    const float* Wm1    = (const float*)d_in[5];
    const float* bm1    = (const float*)d_in[6];
    const float* Wm2    = (const float*)d_in[7];
    const float* bm2    = (const float*)d_in[8];
    const float* Wlx    = (const float*)d_in[9];
    const float* blx    = (const float*)d_in[10];
    const float* Wrx    = (const float*)d_in[11];
    const float* brx    = (const float*)d_in[12];
    const float* Wex    = (const float*)d_in[13];
    const float* attx   = (const float*)d_in[14];
    const float* biasx  = (const float*)d_in[15];
    const float* Wlh    = (const float*)d_in[16];
    const float* blh    = (const float*)d_in[17];
    const float* Wrh    = (const float*)d_in[18];
    const float* brh    = (const float*)d_in[19];
    const float* Weh    = (const float*)d_in[20];
    const float* atth   = (const float*)d_in[21];
    const float* biash  = (const float*)d_in[22];
    const float* ln_g   = (const float*)d_in[23];
    const float* ln_b   = (const float*)d_in[24];

    char* ws = (char*)d_ws;
    f16*   e16     = (f16*)(ws + 0);              // 25,600,000 B
    f16*   XLt     = (f16*)(ws + 25600000);       // 51,200,000 B  [n][64][8]
    f16*   XRt     = (f16*)(ws + 76800000);       // 51,200,000 B  [n][64][8]
    int*   row_ptr = (int*)(ws + 128000000);      //    200,704 B
    int*   degcur  = (int*)(ws + 128200704);      //    200,704 B
    int2*  sorted  = (int2*)(ws + 128401408);     //  6,400,000 B
    int*   scan_tmp = (int*)(ws + 128401408);     // overlaps sorted (dead before k_fill)
    int*   partials = (int*)(ws + 128401408 + 204800);

    const int* srcp = ei;
    const int* dstp = ei + N_EDGES;

    (void)hipMemsetAsync(degcur, 0, N_NODES * sizeof(int), stream);

    k_edge_mlp<<<(N_EDGES + 255) / 256, 256, 0, stream>>>(eattr, Wm1, bm1, Wm2, bm2,
                                                          dstp, degcur, e16);
    k_node_feats<32><<<6250, 512, 0, stream>>>(x_t, Wlx, blx, Wrx, brx, XLt, XRt, 0);
    k_node_feats<64><<<6250, 512, 0, stream>>>(h_prev, Wlh, blh, Wrh, brh, XLt, XRt, 4);
    k_scan1<<<SCAN_NBLK, SCAN_B, 0, stream>>>(degcur, scan_tmp, partials);
    k_scan2<<<1, 64, 0, stream>>>(partials);
    k_scan3<<<SCAN_NBLK, SCAN_B, 0, stream>>>(scan_tmp, partials, row_ptr, degcur);
    k_fill<<<(N_EDGES + 255) / 256, 256, 0, stream>>>(srcp, dstp, row_ptr, degcur, sorted);
    k_gat_main<<<N_NODES / 4, 256, 0, stream>>>(e16, XLt, XRt, row_ptr, sorted,
                                                Wex, Weh, attx, atth, biasx, biash,
                                                c_prev, ln_g, ln_b, (float*)d_out);
}